// Round 8
// baseline (221.768 us; speedup 1.0000x reference)
//
#include <hip/hip_runtime.h>
#include <hip/hip_bf16.h>

#define B_DIM  8192
#define IN_DIM 1024
#define H_DIM  1024
#define K_DIM  2048   // IN + H
#define BK     64
#define NT     (K_DIM / BK)   // 32

typedef __attribute__((ext_vector_type(8))) short bf16x8;
typedef __attribute__((ext_vector_type(4))) float f32x4;

__device__ __forceinline__ void mfma_16x16x32_bf16(f32x4& d, const bf16x8& a, const bf16x8& b) {
  asm volatile("v_mfma_f32_16x16x32_bf16 %0, %1, %2, %0" : "+v"(d) : "v"(a), "v"(b));
}

__device__ __forceinline__ void gload16(const void* g, void* l) {
  __builtin_amdgcn_global_load_lds(
      (const __attribute__((address_space(1))) void*)g,
      (__attribute__((address_space(3))) void*)l,
      16, 0, 0);
}

__device__ __forceinline__ float fast_sigmoid(float x) {
  return 1.0f / (1.0f + __expf(-x));
}
__device__ __forceinline__ float fast_tanh(float x) {
  float e = __expf(2.0f * x);
  return 1.0f - 2.0f / (e + 1.0f);
}

// ---------------- pack kernels (unchanged, proven) -------------------------
__global__ __launch_bounds__(256) void pack_a_kernel(
    const float* __restrict__ x, const float* __restrict__ hx,
    __hip_bfloat16* __restrict__ A) {
  const int idx = blockIdx.x * 256 + threadIdx.x;
  const int r  = idx >> 8;
  const int kk = (idx & 255) << 3;
  const float* src = (kk < IN_DIM) ? (x + (size_t)r * IN_DIM + kk)
                                   : (hx + (size_t)r * H_DIM + (kk - IN_DIM));
  const float4 v0 = ((const float4*)src)[0];
  const float4 v1 = ((const float4*)src)[1];
  __hip_bfloat16 t[8];
  t[0] = __float2bfloat16(v0.x); t[1] = __float2bfloat16(v0.y);
  t[2] = __float2bfloat16(v0.z); t[3] = __float2bfloat16(v0.w);
  t[4] = __float2bfloat16(v1.x); t[5] = __float2bfloat16(v1.y);
  t[6] = __float2bfloat16(v1.z); t[7] = __float2bfloat16(v1.w);
  *(uint4*)(A + ((size_t)idx << 3)) = *(const uint4*)t;
}

__global__ __launch_bounds__(256) void pack_w_kernel(
    const float* __restrict__ wxi, const float* __restrict__ wxf,
    const float* __restrict__ wxc, const float* __restrict__ wxo,
    const float* __restrict__ whi, const float* __restrict__ whf,
    const float* __restrict__ whc, const float* __restrict__ who,
    __hip_bfloat16* __restrict__ W) {
  const int idx = blockIdx.x * 256 + threadIdx.x;
  const int row = idx >> 8;
  const int kk  = (idx & 255) << 3;
  const int g = row >> 10, n = row & 1023;
  const float* src;
  if (kk < IN_DIM) {
    const float* p = (g == 0) ? wxi : (g == 1) ? wxf : (g == 2) ? wxc : wxo;
    src = p + (size_t)n * IN_DIM + kk;
  } else {
    const float* p = (g == 0) ? whi : (g == 1) ? whf : (g == 2) ? whc : who;
    src = p + (size_t)n * H_DIM + (kk - IN_DIM);
  }
  const float4 v0 = ((const float4*)src)[0];
  const float4 v1 = ((const float4*)src)[1];
  __hip_bfloat16 t[8];
  t[0] = __float2bfloat16(v0.x); t[1] = __float2bfloat16(v0.y);
  t[2] = __float2bfloat16(v0.z); t[3] = __float2bfloat16(v0.w);
  t[4] = __float2bfloat16(v1.x); t[5] = __float2bfloat16(v1.y);
  t[6] = __float2bfloat16(v1.z); t[7] = __float2bfloat16(v1.w);
  *(uint4*)(W + ((size_t)idx << 3)) = *(const uint4*)t;
}

// ---- fused GEMM + LSTM epilogue: A-only LDS DMA, W direct-to-register -----
// R7 postmortem: __launch_bounds__(512,4) capped unified VGPR+AGPR at 128 <
// acc alone (128) -> forced-spill pathology, wrong results. THIS ROUND: the
// single fix is (512,2) = 256 regs (R6's proven budget; design needs ~240).
// Design (unchanged): W fragments load global->VGPR directly (L2-resident
// panel, 64B-coalesced, double-buffered one tile ahead); LDS holds only A
// (4x reuse) = 2 x 32KB. Halves the global_load_lds DMA bytes (the R6-
// diagnosed ~12-20 B/cyc/CU bottleneck): 64KB -> 32KB per tile.
// Per tile: issue {4 A-DMA(t+1) -> other buf, 8 W-loads(t+1) -> other regs};
// 16 ds_read af + 64 MFMA; fused vmcnt(0)+s_barrier (flight = full tile).
// Loop unrolled x2 for static buffer/register parity (no dynamic indexing).
// A chunk-XOR swizzle (proven 0-conflict): content chunk c of row r stored at
// chunk c^(r&7) via pre-swizzled global source; ds_read applies same XOR.
__global__ __launch_bounds__(512, 2) void lstm_gemm_kernel(
    const __hip_bfloat16* __restrict__ A,   // [8192][2048]
    const __hip_bfloat16* __restrict__ W,   // [4096][2048] gate-major
    const float* __restrict__ cx,
    const float* __restrict__ bxi, const float* __restrict__ bhi,
    const float* __restrict__ bxf, const float* __restrict__ bhf,
    const float* __restrict__ bxc, const float* __restrict__ bhc,
    const float* __restrict__ bxo, const float* __restrict__ bho,
    float* __restrict__ hy, float* __restrict__ cy) {

  __shared__ __align__(16) char lds[2][32 * 1024];   // A tiles only

  const int tid  = threadIdx.x;
  const int w    = tid >> 6;
  const int lane = tid & 63;
  const int wm = w >> 2, wn = w & 3;
  const int lq = lane >> 4, lr16 = lane & 15;

  // raster: 32 row-tiles fast, 16 col-tiles slow (W panel L2-resident)
  const int bid = blockIdx.x;                 // 512 blocks
  const int row0 = (bid & 31) * 256;
  const int col0 = (bid >> 5) * 64;

  // A staging: thread -> (row-in-64-row-unit tid>>3, chunk tid&7), source
  // chunk pre-swizzled (c ^ row&7); LDS dest linear tid*16.
  const int srow = tid >> 3;
  const int scs  = (tid & 7) ^ (srow & 7);
  const __hip_bfloat16* Asrc = A + (size_t)(row0 + srow) * K_DIM + scs * 8;

  // W direct-load base for this wave's fragment row
  const size_t Wg = (size_t)H_DIM * K_DIM;    // per-gate stride
  const __hip_bfloat16* Wfrag =
      W + (size_t)(col0 + wn * 16 + lr16) * K_DIM + lq * 8;

  // A ds_read byte offsets with matching XOR; m adds 2048, mh1 adds 8192.
  const int xr = lr16 & 7;
  const int aoff0 = wm * 16384 + lr16 * 128 + ((lq)     ^ xr) * 16;
  const int aoff1 = wm * 16384 + lr16 * 128 + ((4 + lq) ^ xr) * 16;

  f32x4 acc[4][8];
#pragma unroll
  for (int g = 0; g < 4; ++g)
#pragma unroll
    for (int m = 0; m < 8; ++m)
      acc[g][m] = (f32x4){0.f, 0.f, 0.f, 0.f};

#define STAGE_A(Q, KT)                                                        \
  {                                                                           \
    const size_t kof = (size_t)(KT) * BK;                                     \
    gload16(Asrc + kof,               &lds[Q][tid * 16]);                     \
    gload16(Asrc + 64 * K_DIM + kof,  &lds[Q][8192  + tid * 16]);             \
    gload16(Asrc + 128 * K_DIM + kof, &lds[Q][16384 + tid * 16]);             \
    gload16(Asrc + 192 * K_DIM + kof, &lds[Q][24576 + tid * 16]);             \
  }
#define LOAD_W(DST, KT)                                                       \
  {                                                                           \
    const size_t kof = (size_t)(KT) * BK;                                     \
    _Pragma("unroll")                                                         \
    for (int g = 0; g < 4; ++g) {                                             \
      DST[g][0] = *(const bf16x8*)(Wfrag + (size_t)g * Wg + kof);             \
      DST[g][1] = *(const bf16x8*)(Wfrag + (size_t)g * Wg + kof + 32);        \
    }                                                                         \
  }
#define TILE_COMPUTE(P, WF)                                                   \
  {                                                                           \
    const char* rb = lds[P];                                                  \
    bf16x8 af0[4][2], af1[4][2];                                              \
    _Pragma("unroll")                                                         \
    for (int m = 0; m < 4; ++m) {                                             \
      af0[m][0] = *(const bf16x8*)(rb + aoff0 + m * 2048);                    \
      af0[m][1] = *(const bf16x8*)(rb + aoff1 + m * 2048);                    \
    }                                                                         \
    __builtin_amdgcn_s_setprio(1);                                            \
    _Pragma("unroll")                                                         \
    for (int g = 0; g < 4; ++g)                                               \
      _Pragma("unroll")                                                       \
      for (int m = 0; m < 4; ++m) {                                           \
        mfma_16x16x32_bf16(acc[g][m], af0[m][0], WF[g][0]);                   \
        mfma_16x16x32_bf16(acc[g][m], af0[m][1], WF[g][1]);                   \
      }                                                                       \
    __builtin_amdgcn_s_setprio(0);                                            \
    _Pragma("unroll")                                                         \
    for (int m = 0; m < 4; ++m) {                                             \
      af1[m][0] = *(const bf16x8*)(rb + aoff0 + 8192 + m * 2048);             \
      af1[m][1] = *(const bf16x8*)(rb + aoff1 + 8192 + m * 2048);             \
    }                                                                         \
    __builtin_amdgcn_s_setprio(1);                                            \
    _Pragma("unroll")                                                         \
    for (int g = 0; g < 4; ++g)                                               \
      _Pragma("unroll")                                                       \
      for (int m = 0; m < 4; ++m) {                                           \
        mfma_16x16x32_bf16(acc[g][4 + m], af1[m][0], WF[g][0]);               \
        mfma_16x16x32_bf16(acc[g][4 + m], af1[m][1], WF[g][1]);               \
      }                                                                       \
    __builtin_amdgcn_s_setprio(0);                                            \
  }
#define SYNC()  asm volatile("s_waitcnt vmcnt(0)\n\ts_barrier" ::: "memory")

  bf16x8 wfA[4][2], wfB[4][2];

  // prologue: tile0 -> buf0 + wfA; confirm
  STAGE_A(0, 0);
  LOAD_W(wfA, 0);
  SYNC();

#pragma unroll 1
  for (int t = 0; t < NT; t += 2) {
    // ---- even tile t: read buf0/wfA; prefetch t+1 -> buf1/wfB ----
    {
      const int tn = (t + 1 < NT) ? t + 1 : NT - 1;
      STAGE_A(1, tn);
      LOAD_W(wfB, tn);
      TILE_COMPUTE(0, wfA);
      SYNC();
    }
    // ---- odd tile t+1: read buf1/wfB; prefetch t+2 -> buf0/wfA ----
    {
      const int tn = (t + 2 < NT) ? t + 2 : NT - 1;  // clamp: uniform counts
      STAGE_A(0, tn);
      LOAD_W(wfA, tn);
      TILE_COMPUTE(1, wfB);
      SYNC();
    }
  }

  // ---- epilogue: gates + cell update (wave-local, all 4 gates in-wave) ----
  const int h = col0 + wn * 16 + lr16;
  const float bi  = bxi[h] + bhi[h];
  const float bff = bxf[h] + bhf[h];
  const float bc  = bxc[h] + bhc[h];
  const float bo  = bxo[h] + bho[h];
#pragma unroll
  for (int m = 0; m < 8; ++m) {
#pragma unroll
    for (int j = 0; j < 4; ++j) {
      const int r = row0 + wm * 128 + m * 16 + lq * 4 + j;
      const size_t o = (size_t)r * H_DIM + h;
      const float ig = fast_sigmoid(acc[0][m][j] + bi);
      const float fg = fast_sigmoid(acc[1][m][j] + bff);
      const float gg = fast_tanh   (acc[2][m][j] + bc);
      const float og = fast_sigmoid(acc[3][m][j] + bo);
      const float c  = cx[o] * fg + ig * gg;
      cy[o] = c;
      hy[o] = og * fast_tanh(c);
    }
  }
#undef STAGE_A
#undef LOAD_W
#undef TILE_COMPUTE
#undef SYNC
}

extern "C" void kernel_launch(void* const* d_in, const int* in_sizes, int n_in,
                              void* d_out, int out_size, void* d_ws, size_t ws_size,
                              hipStream_t stream) {
  const float* x   = (const float*)d_in[0];
  const float* hx  = (const float*)d_in[1];
  const float* cx  = (const float*)d_in[2];
  const float* wxi = (const float*)d_in[4];  const float* bxi = (const float*)d_in[5];
  const float* wxf = (const float*)d_in[6];  const float* bxf = (const float*)d_in[7];
  const float* wxc = (const float*)d_in[8];  const float* bxc = (const float*)d_in[9];
  const float* wxo = (const float*)d_in[10]; const float* bxo = (const float*)d_in[11];
  const float* whi = (const float*)d_in[12]; const float* bhi = (const float*)d_in[13];
  const float* whf = (const float*)d_in[14]; const float* bhf = (const float*)d_in[15];
  const float* whc = (const float*)d_in[16]; const float* bhc = (const float*)d_in[17];
  const float* who = (const float*)d_in[18]; const float* bho = (const float*)d_in[19];

  __hip_bfloat16* Abf = (__hip_bfloat16*)d_ws;
  __hip_bfloat16* Wbf = (__hip_bfloat16*)((char*)d_ws + (size_t)B_DIM * K_DIM * 2);

  float* hy  = (float*)d_out;
  float* cyo = (float*)d_out + (size_t)B_DIM * H_DIM;

  pack_a_kernel<<<(B_DIM * K_DIM / 8) / 256, 256, 0, stream>>>(x, hx, Abf);
  pack_w_kernel<<<(4 * H_DIM * K_DIM / 8) / 256, 256, 0, stream>>>(
      wxi, wxf, wxc, wxo, whi, whf, whc, who, Wbf);

  lstm_gemm_kernel<<<dim3(512), 512, 0, stream>>>(
      Abf, Wbf, cx, bxi, bhi, bxf, bhf, bxc, bhc, bxo, bho, hy, cyo);
}

// Round 9
// 158.867 us; speedup vs baseline: 1.3959x; 1.3959x over previous
//
#include <hip/hip_runtime.h>
#include <hip/hip_bf16.h>

#define B_DIM  8192
#define IN_DIM 1024
#define H_DIM  1024
#define K_DIM  2048   // IN + H
#define BK     64
#define NT     (K_DIM / BK)   // 32

typedef __attribute__((ext_vector_type(8))) short bf16x8;
typedef __attribute__((ext_vector_type(4))) float f32x4;

__device__ __forceinline__ void mfma_16x16x32_bf16(f32x4& d, const bf16x8& a, const bf16x8& b) {
  asm volatile("v_mfma_f32_16x16x32_bf16 %0, %1, %2, %0" : "+v"(d) : "v"(a), "v"(b));
}

__device__ __forceinline__ void gload16(const void* g, void* l) {
  __builtin_amdgcn_global_load_lds(
      (const __attribute__((address_space(1))) void*)g,
      (__attribute__((address_space(3))) void*)l,
      16, 0, 0);
}

__device__ __forceinline__ float fast_sigmoid(float x) {
  return 1.0f / (1.0f + __expf(-x));
}
__device__ __forceinline__ float fast_tanh(float x) {
  float e = __expf(2.0f * x);
  return 1.0f - 2.0f / (e + 1.0f);
}

// ---------------- pack kernels (unchanged, proven) -------------------------
__global__ __launch_bounds__(256) void pack_a_kernel(
    const float* __restrict__ x, const float* __restrict__ hx,
    __hip_bfloat16* __restrict__ A) {
  const int idx = blockIdx.x * 256 + threadIdx.x;
  const int r  = idx >> 8;
  const int kk = (idx & 255) << 3;
  const float* src = (kk < IN_DIM) ? (x + (size_t)r * IN_DIM + kk)
                                   : (hx + (size_t)r * H_DIM + (kk - IN_DIM));
  const float4 v0 = ((const float4*)src)[0];
  const float4 v1 = ((const float4*)src)[1];
  __hip_bfloat16 t[8];
  t[0] = __float2bfloat16(v0.x); t[1] = __float2bfloat16(v0.y);
  t[2] = __float2bfloat16(v0.z); t[3] = __float2bfloat16(v0.w);
  t[4] = __float2bfloat16(v1.x); t[5] = __float2bfloat16(v1.y);
  t[6] = __float2bfloat16(v1.z); t[7] = __float2bfloat16(v1.w);
  *(uint4*)(A + ((size_t)idx << 3)) = *(const uint4*)t;
}

__global__ __launch_bounds__(256) void pack_w_kernel(
    const float* __restrict__ wxi, const float* __restrict__ wxf,
    const float* __restrict__ wxc, const float* __restrict__ wxo,
    const float* __restrict__ whi, const float* __restrict__ whf,
    const float* __restrict__ whc, const float* __restrict__ who,
    __hip_bfloat16* __restrict__ W) {
  const int idx = blockIdx.x * 256 + threadIdx.x;
  const int row = idx >> 8;
  const int kk  = (idx & 255) << 3;
  const int g = row >> 10, n = row & 1023;
  const float* src;
  if (kk < IN_DIM) {
    const float* p = (g == 0) ? wxi : (g == 1) ? wxf : (g == 2) ? wxc : wxo;
    src = p + (size_t)n * IN_DIM + kk;
  } else {
    const float* p = (g == 0) ? whi : (g == 1) ? whf : (g == 2) ? whc : who;
    src = p + (size_t)n * H_DIM + (kk - IN_DIM);
  }
  const float4 v0 = ((const float4*)src)[0];
  const float4 v1 = ((const float4*)src)[1];
  __hip_bfloat16 t[8];
  t[0] = __float2bfloat16(v0.x); t[1] = __float2bfloat16(v0.y);
  t[2] = __float2bfloat16(v0.z); t[3] = __float2bfloat16(v0.w);
  t[4] = __float2bfloat16(v1.x); t[5] = __float2bfloat16(v1.y);
  t[6] = __float2bfloat16(v1.z); t[7] = __float2bfloat16(v1.w);
  *(uint4*)(W + ((size_t)idx << 3)) = *(const uint4*)t;
}

// --- fused GEMM + LSTM epilogue: spread-issue counted-vmcnt (m201-style) ---
// Cross-round law: DMA delivery ~12 B/cyc/CU when the queue drains once per
// tile (R6); ~20 B/cyc when it never empties (m201). This kernel keeps >=4
// loads/wave in flight continuously.
// Geometry = R6 (proven addressing): 512 thr / 8 waves (wm=w>>2 row-half,
// wn=w&3 h-quarter); tile 256 rows x 64h x 4 gates; BK=64; LDS 128KB =
// 2 bufs x (A 32KB [4 segs of 64 rows] + W 32KB [4 gates]).
// Stage units (2 gloads each): u1=A segs{0,2}, u2=W g01, u3=W g23,
// u4=A segs{1,3}. Unit u_k(t+1) issued at phase P_{k-1}(t); flights 2-3
// phases (>=1300cyc > 900 HBM).
// Phases (1 barrier each; quadrant MFMA = R5's proven order):
//  P0: rd af_lo+wf01 | issue u1(t+1) | vmcnt(4)+BAR | MFMA (g01,m0-3)
//  P1: rd wf23       | issue u2(t+1) | vmcnt(4)+BAR | MFMA (g23,m0-3)
//  P2: rd af_hi      | issue u3(t+1) |          BAR | MFMA (g23,m4-7)
//  P3:               | issue u4(t+1) | vmcnt(4)+BAR | MFMA (g01,m4-7) [wf01 reuse]
// Confirm matrix: P3(t-1) confirms u1,u2(t); P0(t) confirms u3(t); P1(t)
// confirms u4(t); P2 needs no wait. Overwrite of any region is >=3 barriers
// after its last read (regions read exactly once/tile, frags held in regs).
// Chunk-XOR swizzle (proven 0-conflict) via pre-swizzled global source.
__global__ __launch_bounds__(512, 2) void lstm_gemm_kernel(
    const __hip_bfloat16* __restrict__ A,   // [8192][2048]
    const __hip_bfloat16* __restrict__ W,   // [4096][2048] gate-major
    const float* __restrict__ cx,
    const float* __restrict__ bxi, const float* __restrict__ bhi,
    const float* __restrict__ bxf, const float* __restrict__ bhf,
    const float* __restrict__ bxc, const float* __restrict__ bhc,
    const float* __restrict__ bxo, const float* __restrict__ bho,
    float* __restrict__ hy, float* __restrict__ cy) {

  __shared__ __align__(16) char lds[2][64 * 1024];  // per buf: A@0, W@32768

  const int tid  = threadIdx.x;
  const int w    = tid >> 6;
  const int lane = tid & 63;
  const int wm = w >> 2, wn = w & 3;
  const int lq = lane >> 4, lr16 = lane & 15;

  // bijective XCD swizzle (512%8==0): XCD k owns 2 col-panels, W L2-resident
  const int bid = blockIdx.x;
  const int swz = (bid & 7) * 64 + (bid >> 3);
  const int row0 = (swz & 31) * 256;
  const int col0 = (swz >> 5) * 64;

  // staging: thread -> (row-in-64-row-unit tid>>3, chunk tid&7), source chunk
  // pre-swizzled (c ^ row&7); LDS dest linear tid*16.
  const int srow = tid >> 3;
  const int scs  = (tid & 7) ^ (srow & 7);
  const __hip_bfloat16* Asrc = A + (size_t)(row0 + srow) * K_DIM + scs * 8;
  const __hip_bfloat16* Wsrc = W + (size_t)(col0 + srow) * K_DIM + scs * 8;
  const size_t Wg = (size_t)H_DIM * K_DIM;

  // ds_read byte offsets with matching XOR (R5/R6-proven)
  const int xr = lr16 & 7;
  const int aoff0 = wm * 16384 + lr16 * 128 + ((lq)     ^ xr) * 16;
  const int aoff1 = wm * 16384 + lr16 * 128 + ((4 + lq) ^ xr) * 16;
  const int woff0 = 32768 + (wn * 16 + lr16) * 128 + ((lq)     ^ xr) * 16;
  const int woff1 = 32768 + (wn * 16 + lr16) * 128 + ((4 + lq) ^ xr) * 16;

  f32x4 acc[4][8];
#pragma unroll
  for (int g = 0; g < 4; ++g)
#pragma unroll
    for (int m = 0; m < 8; ++m)
      acc[g][m] = (f32x4){0.f, 0.f, 0.f, 0.f};

#define STAGE_U1(Q, KT)                                                       \
  {                                                                           \
    const size_t kof = (size_t)(KT) * BK;                                     \
    gload16(Asrc + kof,               &lds[Q][tid * 16]);                     \
    gload16(Asrc + 128 * K_DIM + kof, &lds[Q][16384 + tid * 16]);             \
  }
#define STAGE_U4(Q, KT)                                                       \
  {                                                                           \
    const size_t kof = (size_t)(KT) * BK;                                     \
    gload16(Asrc + 64 * K_DIM + kof,  &lds[Q][8192  + tid * 16]);             \
    gload16(Asrc + 192 * K_DIM + kof, &lds[Q][24576 + tid * 16]);             \
  }
#define STAGE_U2(Q, KT)                                                       \
  {                                                                           \
    const size_t kof = (size_t)(KT) * BK;                                     \
    gload16(Wsrc + kof,          &lds[Q][32768 + tid * 16]);                  \
    gload16(Wsrc + Wg + kof,     &lds[Q][40960 + tid * 16]);                  \
  }
#define STAGE_U3(Q, KT)                                                       \
  {                                                                           \
    const size_t kof = (size_t)(KT) * BK;                                     \
    gload16(Wsrc + 2 * Wg + kof, &lds[Q][49152 + tid * 16]);                  \
    gload16(Wsrc + 3 * Wg + kof, &lds[Q][57344 + tid * 16]);                  \
  }
#define WAIT4_BAR() asm volatile("s_waitcnt vmcnt(4)\n\ts_barrier" ::: "memory")
#define BAR()       asm volatile("s_barrier" ::: "memory")

  // prologue: all 4 units of tile0 -> buf0; confirm u1,u2 (keep u3,u4 flying)
  STAGE_U1(0, 0);
  STAGE_U2(0, 0);
  STAGE_U3(0, 0);
  STAGE_U4(0, 0);
  WAIT4_BAR();

  bf16x8 af[4][2], wf01[2][2], wf23[2][2];

  for (int t = 0; t < NT; ++t) {
    const int p = t & 1, q = p ^ 1;
    const int tn = (t + 1 < NT) ? t + 1 : NT - 1;   // clamp: uniform counts
    const char* rb = lds[p];

    // ---- P0: rd af_lo + wf01; issue u1(t+1); vmcnt(4) confirms u3(t) ----
#pragma unroll
    for (int m = 0; m < 4; ++m) {
      af[m][0] = *(const bf16x8*)(rb + aoff0 + m * 2048);
      af[m][1] = *(const bf16x8*)(rb + aoff1 + m * 2048);
    }
#pragma unroll
    for (int gi = 0; gi < 2; ++gi) {
      wf01[gi][0] = *(const bf16x8*)(rb + woff0 + gi * 8192);
      wf01[gi][1] = *(const bf16x8*)(rb + woff1 + gi * 8192);
    }
    STAGE_U1(q, tn);
    WAIT4_BAR();
    __builtin_amdgcn_s_setprio(1);
#pragma unroll
    for (int gi = 0; gi < 2; ++gi)
#pragma unroll
      for (int m = 0; m < 4; ++m) {
        mfma_16x16x32_bf16(acc[gi][m], af[m][0], wf01[gi][0]);
        mfma_16x16x32_bf16(acc[gi][m], af[m][1], wf01[gi][1]);
      }
    __builtin_amdgcn_s_setprio(0);

    // ---- P1: rd wf23; issue u2(t+1); vmcnt(4) confirms u4(t) ----
#pragma unroll
    for (int gi = 0; gi < 2; ++gi) {
      wf23[gi][0] = *(const bf16x8*)(rb + woff0 + (2 + gi) * 8192);
      wf23[gi][1] = *(const bf16x8*)(rb + woff1 + (2 + gi) * 8192);
    }
    STAGE_U2(q, tn);
    WAIT4_BAR();
    __builtin_amdgcn_s_setprio(1);
#pragma unroll
    for (int gi = 0; gi < 2; ++gi)
#pragma unroll
      for (int m = 0; m < 4; ++m) {
        mfma_16x16x32_bf16(acc[2 + gi][m], af[m][0], wf23[gi][0]);
        mfma_16x16x32_bf16(acc[2 + gi][m], af[m][1], wf23[gi][1]);
      }
    __builtin_amdgcn_s_setprio(0);

    // ---- P2: rd af_hi; issue u3(t+1); barrier only (no wait needed) ----
#pragma unroll
    for (int m = 0; m < 4; ++m) {
      af[m][0] = *(const bf16x8*)(rb + aoff0 + 8192 + m * 2048);
      af[m][1] = *(const bf16x8*)(rb + aoff1 + 8192 + m * 2048);
    }
    STAGE_U3(q, tn);
    BAR();
    __builtin_amdgcn_s_setprio(1);
#pragma unroll
    for (int gi = 0; gi < 2; ++gi)
#pragma unroll
      for (int m = 0; m < 4; ++m) {
        mfma_16x16x32_bf16(acc[2 + gi][4 + m], af[m][0], wf23[gi][0]);
        mfma_16x16x32_bf16(acc[2 + gi][4 + m], af[m][1], wf23[gi][1]);
      }
    __builtin_amdgcn_s_setprio(0);

    // ---- P3: issue u4(t+1); vmcnt(4) confirms u1,u2(t+1); wf01 reg-reuse --
    STAGE_U4(q, tn);
    WAIT4_BAR();
    __builtin_amdgcn_s_setprio(1);
#pragma unroll
    for (int gi = 0; gi < 2; ++gi)
#pragma unroll
      for (int m = 0; m < 4; ++m) {
        mfma_16x16x32_bf16(acc[gi][4 + m], af[m][0], wf01[gi][0]);
        mfma_16x16x32_bf16(acc[gi][4 + m], af[m][1], wf01[gi][1]);
      }
    __builtin_amdgcn_s_setprio(0);
  }

  // drain redundant tail DMAs before the block's LDS is recycled
  asm volatile("s_waitcnt vmcnt(0)" ::: "memory");

  // ---- epilogue: gates + cell update (wave-local, all 4 gates in-wave) ----
  const int h = col0 + wn * 16 + lr16;
  const float bi  = bxi[h] + bhi[h];
  const float bff = bxf[h] + bhf[h];
  const float bc  = bxc[h] + bhc[h];
  const float bo  = bxo[h] + bho[h];
#pragma unroll
  for (int m = 0; m < 8; ++m) {
#pragma unroll
    for (int j = 0; j < 4; ++j) {
      const int r = row0 + wm * 128 + m * 16 + lq * 4 + j;
      const size_t o = (size_t)r * H_DIM + h;
      const float ig = fast_sigmoid(acc[0][m][j] + bi);
      const float fg = fast_sigmoid(acc[1][m][j] + bff);
      const float gg = fast_tanh   (acc[2][m][j] + bc);
      const float og = fast_sigmoid(acc[3][m][j] + bo);
      const float c  = cx[o] * fg + ig * gg;
      cy[o] = c;
      hy[o] = og * fast_tanh(c);
    }
  }
#undef STAGE_U1
#undef STAGE_U2
#undef STAGE_U3
#undef STAGE_U4
#undef WAIT4_BAR
#undef BAR
}

extern "C" void kernel_launch(void* const* d_in, const int* in_sizes, int n_in,
                              void* d_out, int out_size, void* d_ws, size_t ws_size,
                              hipStream_t stream) {
  const float* x   = (const float*)d_in[0];
  const float* hx  = (const float*)d_in[1];
  const float* cx  = (const float*)d_in[2];
  const float* wxi = (const float*)d_in[4];  const float* bxi = (const float*)d_in[5];
  const float* wxf = (const float*)d_in[6];  const float* bxf = (const float*)d_in[7];
  const float* wxc = (const float*)d_in[8];  const float* bxc = (const float*)d_in[9];
  const float* wxo = (const float*)d_in[10]; const float* bxo = (const float*)d_in[11];
  const float* whi = (const float*)d_in[12]; const float* bhi = (const float*)d_in[13];
  const float* whf = (const float*)d_in[14]; const float* bhf = (const float*)d_in[15];
  const float* whc = (const float*)d_in[16]; const float* bhc = (const float*)d_in[17];
  const float* who = (const float*)d_in[18]; const float* bho = (const float*)d_in[19];

  __hip_bfloat16* Abf = (__hip_bfloat16*)d_ws;
  __hip_bfloat16* Wbf = (__hip_bfloat16*)((char*)d_ws + (size_t)B_DIM * K_DIM * 2);

  float* hy  = (float*)d_out;
  float* cyo = (float*)d_out + (size_t)B_DIM * H_DIM;

  pack_a_kernel<<<(B_DIM * K_DIM / 8) / 256, 256, 0, stream>>>(x, hx, Abf);
  pack_w_kernel<<<(4 * H_DIM * K_DIM / 8) / 256, 256, 0, stream>>>(
      wxi, wxf, wxc, wxo, whi, whf, whc, who, Wbf);

  lstm_gemm_kernel<<<dim3(512), 512, 0, stream>>>(
      Abf, Wbf, cx, bxi, bhi, bxf, bhf, bxc, bhc, bxo, bho, hy, cyo);
}